// Round 2
// baseline (274.198 us; speedup 1.0000x reference)
//
#include <hip/hip_runtime.h>
#include <hip/hip_bf16.h>

// Attention: out = softmax_causal((xWq+bq)(xWk+bk)^T / sqrt(D)) (xWv+bv) Wo + bo
// B=4, S=2048, D=1024.  All GEMMs in bf16 MFMA (16x16x32), fp32 accumulate.
// R2: merged QKV projection (N=3072, 1536 blocks), BM=64 tiles for the
//     skinny GEMMs (QK^T / PV / out-proj) to raise occupancy 2->4+ blocks/CU.

typedef __bf16 bf16x8 __attribute__((ext_vector_type(8)));
typedef __bf16 bf16x4 __attribute__((ext_vector_type(4)));
typedef float  f32x4  __attribute__((ext_vector_type(4)));

#define BDIM 1024
#define SDIM 2048
#define BATCH 4

__device__ __forceinline__ void gload_lds16(const void* g, void* l) {
    __builtin_amdgcn_global_load_lds(
        (const __attribute__((address_space(1))) void*)g,
        (__attribute__((address_space(3))) void*)l, 16, 0, 0);
}

// ---------------- fp32 -> bf16 elementwise ----------------
__global__ __launch_bounds__(256) void cvt_f32_bf16(const float* __restrict__ in,
                                                    __bf16* __restrict__ out, long n) {
    long i = ((long)blockIdx.x * 256 + threadIdx.x) * 4;
    if (i + 3 < n) {
        float4 v = *(const float4*)(in + i);
        bf16x4 o;
        o[0] = (__bf16)v.x; o[1] = (__bf16)v.y; o[2] = (__bf16)v.z; o[3] = (__bf16)v.w;
        *(bf16x4*)(out + i) = o;
    }
}

// ---------------- bias concat [bq|bk|bv] -> bcat[3072] ----------------
__global__ __launch_bounds__(256) void concat3(const float* __restrict__ a,
                                               const float* __restrict__ b,
                                               const float* __restrict__ c,
                                               float* __restrict__ o) {
    int i = blockIdx.x * 256 + threadIdx.x;
    if (i < 3072)
        o[i] = (i < 1024) ? a[i] : ((i < 2048) ? b[i - 1024] : c[i - 2048]);
}

// ---------------- transpose (fp32 or bf16 in) -> bf16 out ----------------
// out[c][r] = in[r][c]; input tile grid: x over cols, y over rows, z batch.
template <typename Tin>
__global__ __launch_bounds__(256) void transpose_to_bf16(const Tin* __restrict__ in,
                                                         __bf16* __restrict__ out,
                                                         int ldIn, int ldOut,
                                                         long sIn, long sOut) {
    __shared__ float tile[32][33];
    const long b = blockIdx.z;
    in += b * sIn; out += b * sOut;
    const int r0 = blockIdx.y * 32, c0 = blockIdx.x * 32;
    const int tx = threadIdx.x, ty = threadIdx.y;  // block (32,8)
    #pragma unroll
    for (int j = ty; j < 32; j += 8)
        tile[j][tx] = (float)in[(long)(r0 + j) * ldIn + (c0 + tx)];
    __syncthreads();
    #pragma unroll
    for (int j = ty; j < 32; j += 8)
        out[(long)(c0 + j) * ldOut + (r0 + tx)] = (__bf16)tile[tx][j];
}

// ---------------- BT GEMM: C[M,N] = A[M,K_d] * B[N,K_d]^T (+bias) -------------
// A, B row-major with leading dims lda/ldb (>= K depth). BM x 128 tile, BK=64,
// 4 waves, 16x16x32 MFMA.  BM in {64,128}.
//   BM=128: waves on 64x64 quadrants, acc[4][4].
//   BM= 64: waves on 32x64 quadrants, acc[2][4].
// CSKIP: skip tiles entirely above the causal diagonal.
// CKB:   bound K-loop to by*BM+BM (PV: P is causally zero past the q tile).
template <typename Tout, int BM, bool CSKIP, bool CKB>
__global__ __launch_bounds__(256) void gemm_bt(const __bf16* __restrict__ Ag,
                                               const __bf16* __restrict__ Bg,
                                               Tout* __restrict__ Cg,
                                               const float* __restrict__ bias,
                                               int N, int K, int lda, int ldb, int ldc,
                                               long sA, long sB, long sC) {
    const int bx = blockIdx.x, by = blockIdx.y;
    if (CSKIP && bx * 128 > by * BM + BM - 1) return;  // fully masked tile
    const __bf16* A = Ag + (long)blockIdx.z * sA;
    const __bf16* B = Bg + (long)blockIdx.z * sB;
    Tout* C = Cg + (long)blockIdx.z * sC;

    constexpr int MI = BM / 32;          // A staging iterations (32 rows each)
    constexpr int MF = BM / 32 / 2;      // A fragment count per wave-row dim
    __shared__ __align__(16) __bf16 As[BM * 64];
    __shared__ __align__(16) __bf16 Bs[128 * 64];

    const int tid = threadIdx.x;
    const int w = tid >> 6, l = tid & 63;
    const int m0 = by * BM, n0 = bx * 128;
    const int wr = (w >> 1) * (BM / 2), wc = (w & 1) * 64;  // wave quadrant
    const int fr = l & 15, fk = (l >> 4) * 8;               // fragment row/k
    const int srow = tid >> 3;                              // staging row [0,32)
    const int skk = (tid & 7) * 8;                          // staging k offset
    const int kEnd = CKB ? min(K, by * BM + BM) : K;

    f32x4 acc[MF * 2][4] = {};

    for (int k0 = 0; k0 < kEnd; k0 += 64) {
        #pragma unroll
        for (int it = 0; it < MI; ++it)
            gload_lds16(A + (long)(m0 + it * 32 + srow) * lda + (k0 + skk),
                        As + it * 2048 + w * 512);
        #pragma unroll
        for (int it = 0; it < 4; ++it)
            gload_lds16(B + (long)(n0 + it * 32 + srow) * ldb + (k0 + skk),
                        Bs + it * 2048 + w * 512);
        __syncthreads();  // drains vmcnt before ds_read
        #pragma unroll
        for (int ks = 0; ks < 2; ++ks) {
            bf16x8 af[MF * 2], bf[4];
            #pragma unroll
            for (int i = 0; i < MF * 2; ++i)
                af[i] = *(const bf16x8*)(As + (wr + i * 16 + fr) * 64 + ks * 32 + fk);
            #pragma unroll
            for (int j = 0; j < 4; ++j)
                bf[j] = *(const bf16x8*)(Bs + (wc + j * 16 + fr) * 64 + ks * 32 + fk);
            #pragma unroll
            for (int i = 0; i < MF * 2; ++i)
                #pragma unroll
                for (int j = 0; j < 4; ++j)
                    acc[i][j] = __builtin_amdgcn_mfma_f32_16x16x32_bf16(af[i], bf[j],
                                                                        acc[i][j], 0, 0, 0);
        }
        __syncthreads();
    }

    // epilogue: C/D layout col = lane&15, row = (lane>>4)*4 + reg  [m89-verified]
    const int rbase = (l >> 4) * 4;
    const int cl = l & 15;
    #pragma unroll
    for (int j = 0; j < 4; ++j) {
        const int col = n0 + wc + j * 16 + cl;
        const float bv = bias ? bias[col] : 0.f;
        #pragma unroll
        for (int i = 0; i < MF * 2; ++i)
            #pragma unroll
            for (int r = 0; r < 4; ++r) {
                const int rowi = m0 + wr + i * 16 + rbase + r;
                C[(long)rowi * ldc + col] = (Tout)(acc[i][j][r] + bv);
            }
    }
}

// ---------------- causal softmax row kernel ----------------
// P[q][k] = softmax_k(scale * scores[q][k], k <= q), zeros for k > q.
__global__ __launch_bounds__(256) void softmax_causal(const __bf16* __restrict__ scores,
                                                      __bf16* __restrict__ P, float scale) {
    const int q = blockIdx.x;
    const long b = blockIdx.y;
    const __bf16* srow = scores + (b * SDIM + q) * (long)SDIM;
    __bf16* prow = P + (b * SDIM + q) * (long)SDIM;
    const int n = q + 1;
    const int tid = threadIdx.x;
    __shared__ float red[8];

    float vals[8];
    float mx = -1e30f;
    #pragma unroll
    for (int i = 0; i < 8; ++i) {
        const int k = i * 256 + tid;
        const float s = (k < n) ? (float)srow[k] * scale : -1e30f;
        vals[i] = s;
        mx = fmaxf(mx, s);
    }
    #pragma unroll
    for (int o = 32; o > 0; o >>= 1) mx = fmaxf(mx, __shfl_xor(mx, o));
    if ((tid & 63) == 0) red[tid >> 6] = mx;
    __syncthreads();
    mx = fmaxf(fmaxf(red[0], red[1]), fmaxf(red[2], red[3]));

    float p[8];
    float sum = 0.f;
    #pragma unroll
    for (int i = 0; i < 8; ++i) {
        p[i] = __expf(vals[i] - mx);  // masked lanes: exp(-huge) -> 0
        sum += p[i];
    }
    #pragma unroll
    for (int o = 32; o > 0; o >>= 1) sum += __shfl_xor(sum, o);
    if ((tid & 63) == 0) red[4 + (tid >> 6)] = sum;
    __syncthreads();
    sum = red[4] + red[5] + red[6] + red[7];

    const float inv = 1.f / sum;
    #pragma unroll
    for (int i = 0; i < 8; ++i) {
        const int k = i * 256 + tid;
        prow[k] = (__bf16)((k < n) ? p[i] * inv : 0.f);
    }
}

extern "C" void kernel_launch(void* const* d_in, const int* in_sizes, int n_in,
                              void* d_out, int out_size, void* d_ws, size_t ws_size,
                              hipStream_t stream) {
    const float* x  = (const float*)d_in[0];
    // d_in[1] = mask (tril ones) -- causality enforced by index, unused.
    const float* Wq = (const float*)d_in[2];
    const float* bq = (const float*)d_in[3];
    const float* Wk = (const float*)d_in[4];
    const float* bk = (const float*)d_in[5];
    const float* Wv = (const float*)d_in[6];
    const float* bv = (const float*)d_in[7];
    const float* Wo = (const float*)d_in[8];
    const float* bo = (const float*)d_in[9];
    float* out = (float*)d_out;

    char* ws = (char*)d_ws;
    const long MT = (long)BATCH * SDIM;           // 8192 total rows
    const long XE = MT * BDIM;                    // 8,388,608 elements
    // workspace layout (bytes)
    __bf16* xb   = (__bf16*)(ws);                 // 16 MiB   [ctx aliases later]
    __bf16* Wcat = (__bf16*)(ws + 16777216);      // 6 MiB   [Wq|Wk|Wv]^T (3072x1024)
    __bf16* Wot  = (__bf16*)(ws + 23068672);      // 2 MiB
    float*  bcat = (float*)(ws + 25165824);       // 12 KiB
    __bf16* QKVb = (__bf16*)(ws + 25178112);      // 48 MiB  (8192 x 3072)
    __bf16* Vtb  = (__bf16*)(ws + 75509760);      // 16 MiB  (B x [1024][2048])
    __bf16* Sc   = (__bf16*)(ws + 92286976);      // 32 MiB  scores
    __bf16* Pb   = (__bf16*)(ws + 25178112);      // alias QKVb (dead after QK^T/Vt)
    __bf16* ctxb = (__bf16*)(ws);                 // alias xb  (dead after QKV proj)

    const long SD  = (long)SDIM * BDIM;           // 2,097,152
    const long SS  = (long)SDIM * SDIM;           // 4,194,304
    const long SQ3 = (long)SDIM * 3 * BDIM;       // 6,291,456 (batch stride in QKVb)

    // 1) x -> bf16
    cvt_f32_bf16<<<dim3((unsigned)(XE / 4 / 256)), 256, 0, stream>>>(x, xb, XE);
    // 2) weights -> transposed bf16; QKV weights packed into Wcat rows [0|1024|2048)
    transpose_to_bf16<float><<<dim3(32, 32, 1), dim3(32, 8), 0, stream>>>(Wq, Wcat,             BDIM, BDIM, 0, 0);
    transpose_to_bf16<float><<<dim3(32, 32, 1), dim3(32, 8), 0, stream>>>(Wk, Wcat + 1024*1024, BDIM, BDIM, 0, 0);
    transpose_to_bf16<float><<<dim3(32, 32, 1), dim3(32, 8), 0, stream>>>(Wv, Wcat + 2048*1024, BDIM, BDIM, 0, 0);
    transpose_to_bf16<float><<<dim3(32, 32, 1), dim3(32, 8), 0, stream>>>(Wo, Wot,              BDIM, BDIM, 0, 0);
    concat3<<<dim3(12), 256, 0, stream>>>(bq, bk, bv, bcat);
    // 3) merged projection: QKV[8192][3072] = x @ Wcat^T + bcat
    gemm_bt<__bf16, 128, false, false><<<dim3(24, 64, 1), 256, 0, stream>>>(
        xb, Wcat, QKVb, bcat, 3072, BDIM, BDIM, BDIM, 3072, 0, 0, 0);
    // 4) V^T per batch: [S,1024] (stride 3072 inside QKV) -> [1024][S]
    transpose_to_bf16<__bf16><<<dim3(32, 64, BATCH), dim3(32, 8), 0, stream>>>(
        QKVb + 2048, Vtb, 3072, SDIM, SQ3, SD);
    // 5) scores = Q @ K^T per batch (causal tile skip), raw logits in bf16
    gemm_bt<__bf16, 64, true, false><<<dim3(16, 32, BATCH), 256, 0, stream>>>(
        QKVb, QKVb + 1024, Sc, nullptr, SDIM, BDIM, 3072, 3072, SDIM, SQ3, SQ3, SS);
    // 6) causal softmax (scale = 1/32)
    softmax_causal<<<dim3(SDIM, BATCH), 256, 0, stream>>>(Sc, Pb, 0.03125f);
    // 7) ctx = P @ V   (B operand = V^T, K-loop causally bounded)
    gemm_bt<__bf16, 64, false, true><<<dim3(8, 32, BATCH), 256, 0, stream>>>(
        Pb, Vtb, ctxb, nullptr, BDIM, SDIM, SDIM, SDIM, BDIM, SS, SD, SD);
    // 8) out = ctx @ Wo + bo (fp32 output)
    gemm_bt<float, 64, false, false><<<dim3(8, 128, 1), 256, 0, stream>>>(
        ctxb, Wot, out, bo, BDIM, BDIM, BDIM, BDIM, BDIM, 0, 0, 0);
}